// Round 1
// baseline (1136.225 us; speedup 1.0000x reference)
//
#include <hip/hip_runtime.h>
#include <stdint.h>

#define NN 50000
#define RR 64
#define EE 20000
#define IND 256
#define OUTD 256
#define EBLK 313   // ceil(EE/64)

typedef __attribute__((ext_vector_type(8))) short bf16x8;
typedef __attribute__((ext_vector_type(4))) float f32x4;

__device__ __forceinline__ unsigned short f2bf(float f) {
  union { float f; unsigned u; } v; v.f = f;
  unsigned r = v.u + 0x7FFFu + ((v.u >> 16) & 1u);   // RNE
  return (unsigned short)(r >> 16);
}

// ---------- build w_t[r][o][i] (bf16) and root_t[o][i] (bf16) into ws ----------
// grid: 256 blocks = (o-block of 4) x (r-group of 16); 256 threads (i = tid)
__global__ __launch_bounds__(256) void k_build(
    const float* __restrict__ att, const float* __restrict__ basis,
    const float* __restrict__ root, unsigned short* __restrict__ wt,
    unsigned short* __restrict__ rt) {
  const int t  = threadIdx.x;        // i
  const int ob = blockIdx.x & 63;    // o-block
  const int rg = blockIdx.x >> 6;    // r-group
  const int o0 = ob * 4;
  float bas[16][4];
#pragma unroll
  for (int b = 0; b < 16; ++b) {
    float4 v = *reinterpret_cast<const float4*>(basis + ((size_t)(b * IND + t)) * OUTD + o0);
    bas[b][0] = v.x; bas[b][1] = v.y; bas[b][2] = v.z; bas[b][3] = v.w;
  }
  for (int rr2 = 0; rr2 < 16; ++rr2) {
    const int r = rg * 16 + rr2;
    const float* ar = att + r * 16;
    float a0 = 0.f, a1 = 0.f, a2 = 0.f, a3 = 0.f;
#pragma unroll
    for (int b = 0; b < 16; ++b) {
      const float a = ar[b];
      a0 += a * bas[b][0]; a1 += a * bas[b][1];
      a2 += a * bas[b][2]; a3 += a * bas[b][3];
    }
    unsigned short* w0 = wt + ((size_t)r * OUTD + o0) * IND + t;
    w0[0 * IND] = f2bf(a0); w0[1 * IND] = f2bf(a1);
    w0[2 * IND] = f2bf(a2); w0[3 * IND] = f2bf(a3);
  }
  if (rg == 0) {
    float4 v = *reinterpret_cast<const float4*>(root + (size_t)t * OUTD + o0);
    rt[(size_t)(o0 + 0) * IND + t] = f2bf(v.x);
    rt[(size_t)(o0 + 1) * IND + t] = f2bf(v.y);
    rt[(size_t)(o0 + 2) * IND + t] = f2bf(v.z);
    rt[(size_t)(o0 + 3) * IND + t] = f2bf(v.w);
  }
}

// ---------- out = x @ root  (bf16 MFMA, direct stores) ----------
__global__ __launch_bounds__(256) void k_root(
    const float* __restrict__ x, const unsigned short* __restrict__ rt,
    float* __restrict__ out) {
  __shared__ unsigned short Al[64 * 256];   // 32 KB, chunk-swizzled
  const int t = threadIdx.x;
  const int m0 = blockIdx.x * 64;
  {
    const int row = t >> 2, c4 = t & 3;
    const int grow = m0 + row;
    const bool ok = grow < NN;
    const float* xr = x + (size_t)grow * IND;
#pragma unroll
    for (int j = 0; j < 8; ++j) {
      const int chunk = c4 * 8 + j;            // 16B = 8 bf16 along k
      union { bf16x8 v; unsigned short u[8]; } pk;
      if (ok) {
        float4 v0 = *reinterpret_cast<const float4*>(xr + chunk * 8);
        float4 v1 = *reinterpret_cast<const float4*>(xr + chunk * 8 + 4);
        pk.u[0]=f2bf(v0.x); pk.u[1]=f2bf(v0.y); pk.u[2]=f2bf(v0.z); pk.u[3]=f2bf(v0.w);
        pk.u[4]=f2bf(v1.x); pk.u[5]=f2bf(v1.y); pk.u[6]=f2bf(v1.z); pk.u[7]=f2bf(v1.w);
      } else {
#pragma unroll
        for (int q = 0; q < 8; ++q) pk.u[q] = 0;
      }
      const int sw = chunk ^ (row & 7);        // T2 XOR swizzle
      *reinterpret_cast<bf16x8*>(&Al[row * 256 + sw * 8]) = pk.v;
    }
  }
  __syncthreads();
  const int lane = t & 63, wave = t >> 6;
  const int n0 = wave * 64;
  const int lc = lane & 15, lg = lane >> 4;
  f32x4 acc[4][4];
  const f32x4 zf = {0.f, 0.f, 0.f, 0.f};
#pragma unroll
  for (int m = 0; m < 4; ++m)
#pragma unroll
    for (int n = 0; n < 4; ++n) acc[m][n] = zf;
#pragma unroll
  for (int ks = 0; ks < 8; ++ks) {
    bf16x8 af[4], bfr[4];
#pragma unroll
    for (int m = 0; m < 4; ++m) {
      const int arow = m * 16 + lc;
      const int sw = (ks * 4 + lg) ^ (arow & 7);
      af[m] = *reinterpret_cast<const bf16x8*>(&Al[arow * 256 + sw * 8]);
    }
#pragma unroll
    for (int n = 0; n < 4; ++n) {
      const int o = n0 + n * 16 + lc;
      bfr[n] = *reinterpret_cast<const bf16x8*>(&rt[(size_t)o * IND + ks * 32 + lg * 8]);
    }
#pragma unroll
    for (int m = 0; m < 4; ++m)
#pragma unroll
      for (int n = 0; n < 4; ++n)
        acc[m][n] = __builtin_amdgcn_mfma_f32_16x16x32_bf16(af[m], bfr[n], acc[m][n], 0, 0, 0);
  }
#pragma unroll
  for (int m = 0; m < 4; ++m) {
#pragma unroll
    for (int j = 0; j < 4; ++j) {
      const int row = m0 + m * 16 + lg * 4 + j;
      if (row < NN) {
        float* orow = out + (size_t)row * OUTD + n0 + lc;
        orow[0]  = acc[m][0][j];
        orow[16] = acc[m][1][j];
        orow[32] = acc[m][2][j];
        orow[48] = acc[m][3][j];
      }
    }
  }
}

// ---------- per-relation gather-GEMM-scatter: out[dst] += (x[src] @ w_r) / deg[dst] ----------
__global__ __launch_bounds__(256) void k_msgs(
    const float* __restrict__ x, const unsigned short* __restrict__ wt,
    const int* __restrict__ esrc, const int* __restrict__ edst,
    const float* __restrict__ deg, float* __restrict__ out) {
  __shared__ unsigned short Al[64 * 256];
  __shared__ int   dstl[64];
  __shared__ float invl[64];
  const int t = threadIdx.x;
  // XCD swizzle: contiguous 2504-block chunk (8 whole relations) per XCD
  const int bid = blockIdx.x;
  const int wg = (bid & 7) * ((RR * EBLK) >> 3) + (bid >> 3);
  const int r  = wg / EBLK;
  const int eb = wg - r * EBLK;

  if (t < 64) {
    const int e = eb * 64 + t;
    int d = -1; float iv = 0.f;
    if (e < EE) { d = edst[(size_t)r * EE + e]; iv = 1.0f / deg[d]; }
    dstl[t] = d; invl[t] = iv;
  }
  {
    const int row = t >> 2, c4 = t & 3;
    const int e = eb * 64 + row;
    const int src = (e < EE) ? esrc[(size_t)r * EE + e] : -1;
    const bool ok = src >= 0;
    const float* xr = x + (size_t)(ok ? src : 0) * IND;
#pragma unroll
    for (int j = 0; j < 8; ++j) {
      const int chunk = c4 * 8 + j;
      union { bf16x8 v; unsigned short u[8]; } pk;
      if (ok) {
        float4 v0 = *reinterpret_cast<const float4*>(xr + chunk * 8);
        float4 v1 = *reinterpret_cast<const float4*>(xr + chunk * 8 + 4);
        pk.u[0]=f2bf(v0.x); pk.u[1]=f2bf(v0.y); pk.u[2]=f2bf(v0.z); pk.u[3]=f2bf(v0.w);
        pk.u[4]=f2bf(v1.x); pk.u[5]=f2bf(v1.y); pk.u[6]=f2bf(v1.z); pk.u[7]=f2bf(v1.w);
      } else {
#pragma unroll
        for (int q = 0; q < 8; ++q) pk.u[q] = 0;
      }
      const int sw = chunk ^ (row & 7);
      *reinterpret_cast<bf16x8*>(&Al[row * 256 + sw * 8]) = pk.v;
    }
  }
  __syncthreads();
  const int lane = t & 63, wave = t >> 6;
  const int n0 = wave * 64;
  const int lc = lane & 15, lg = lane >> 4;
  const unsigned short* Bt = wt + (size_t)r * (OUTD * IND);
  f32x4 acc[4][4];
  const f32x4 zf = {0.f, 0.f, 0.f, 0.f};
#pragma unroll
  for (int m = 0; m < 4; ++m)
#pragma unroll
    for (int n = 0; n < 4; ++n) acc[m][n] = zf;
#pragma unroll
  for (int ks = 0; ks < 8; ++ks) {
    bf16x8 af[4], bfr[4];
#pragma unroll
    for (int m = 0; m < 4; ++m) {
      const int arow = m * 16 + lc;
      const int sw = (ks * 4 + lg) ^ (arow & 7);
      af[m] = *reinterpret_cast<const bf16x8*>(&Al[arow * 256 + sw * 8]);
    }
#pragma unroll
    for (int n = 0; n < 4; ++n) {
      const int o = n0 + n * 16 + lc;
      bfr[n] = *reinterpret_cast<const bf16x8*>(&Bt[(size_t)o * IND + ks * 32 + lg * 8]);
    }
#pragma unroll
    for (int m = 0; m < 4; ++m)
#pragma unroll
      for (int n = 0; n < 4; ++n)
        acc[m][n] = __builtin_amdgcn_mfma_f32_16x16x32_bf16(af[m], bfr[n], acc[m][n], 0, 0, 0);
  }
  // scatter epilogue: 16 lanes hit 16 consecutive dwords (one 64B line) per atomic instr
#pragma unroll
  for (int m = 0; m < 4; ++m) {
#pragma unroll
    for (int j = 0; j < 4; ++j) {
      const int el = m * 16 + lg * 4 + j;
      const int d = dstl[el];
      if (d >= 0) {
        const float iv = invl[el];
        float* orow = out + (size_t)d * OUTD + n0 + lc;
        atomicAdd(orow + 0,  acc[m][0][j] * iv);
        atomicAdd(orow + 16, acc[m][1][j] * iv);
        atomicAdd(orow + 32, acc[m][2][j] * iv);
        atomicAdd(orow + 48, acc[m][3][j] * iv);
      }
    }
  }
}

extern "C" void kernel_launch(void* const* d_in, const int* in_sizes, int n_in,
                              void* d_out, int out_size, void* d_ws, size_t ws_size,
                              hipStream_t stream) {
  (void)in_sizes; (void)n_in; (void)out_size; (void)ws_size;
  const float* x     = (const float*)d_in[0];
  const float* att   = (const float*)d_in[1];
  const float* basis = (const float*)d_in[2];
  const float* root  = (const float*)d_in[3];
  const float* deg   = (const float*)d_in[4];
  const int*   esrc  = (const int*)d_in[5];
  const int*   edst  = (const int*)d_in[6];
  unsigned short* wt = (unsigned short*)d_ws;                 // [R][OUT][IN] bf16, 8.39 MB
  unsigned short* rt = wt + (size_t)RR * OUTD * IND;          // [OUT][IN]  bf16, 128 KB
  float* out = (float*)d_out;

  hipLaunchKernelGGL(k_build, dim3(256), dim3(256), 0, stream, att, basis, root, wt, rt);
  hipLaunchKernelGGL(k_root,  dim3((NN + 63) / 64), dim3(256), 0, stream, x, rt, out);
  hipLaunchKernelGGL(k_msgs,  dim3(RR * EBLK), dim3(256), 0, stream, x, wt, esrc, edst, deg, out);
}

// Round 2
// 917.035 us; speedup vs baseline: 1.2390x; 1.2390x over previous
//
#include <hip/hip_runtime.h>
#include <stdint.h>

#define NN 50000
#define RR 64
#define EE 20000
#define IND 256
#define OUTD 256
#define EBLK 313   // ceil(EE/64)

typedef __attribute__((ext_vector_type(8))) short bf16x8;
typedef __attribute__((ext_vector_type(4))) float f32x4;

__device__ __forceinline__ unsigned short f2bf(float f) {
  union { float f; unsigned u; } v; v.f = f;
  unsigned r = v.u + 0x7FFFu + ((v.u >> 16) & 1u);   // RNE
  return (unsigned short)(r >> 16);
}
__device__ __forceinline__ float bf2f(unsigned short s) {
  union { unsigned u; float f; } v; v.u = ((unsigned)s) << 16;
  return v.f;
}

// ---------- build w_t[r][o][i] (bf16) and root_t[o][i] (bf16) into ws ----------
__global__ __launch_bounds__(256) void k_build(
    const float* __restrict__ att, const float* __restrict__ basis,
    const float* __restrict__ root, unsigned short* __restrict__ wt,
    unsigned short* __restrict__ rt) {
  const int t  = threadIdx.x;        // i
  const int ob = blockIdx.x & 63;    // o-block
  const int rg = blockIdx.x >> 6;    // r-group
  const int o0 = ob * 4;
  float bas[16][4];
#pragma unroll
  for (int b = 0; b < 16; ++b) {
    float4 v = *reinterpret_cast<const float4*>(basis + ((size_t)(b * IND + t)) * OUTD + o0);
    bas[b][0] = v.x; bas[b][1] = v.y; bas[b][2] = v.z; bas[b][3] = v.w;
  }
  for (int rr2 = 0; rr2 < 16; ++rr2) {
    const int r = rg * 16 + rr2;
    const float* ar = att + r * 16;
    float a0 = 0.f, a1 = 0.f, a2 = 0.f, a3 = 0.f;
#pragma unroll
    for (int b = 0; b < 16; ++b) {
      const float a = ar[b];
      a0 += a * bas[b][0]; a1 += a * bas[b][1];
      a2 += a * bas[b][2]; a3 += a * bas[b][3];
    }
    unsigned short* w0 = wt + ((size_t)r * OUTD + o0) * IND + t;
    w0[0 * IND] = f2bf(a0); w0[1 * IND] = f2bf(a1);
    w0[2 * IND] = f2bf(a2); w0[3 * IND] = f2bf(a3);
  }
  if (rg == 0) {
    float4 v = *reinterpret_cast<const float4*>(root + (size_t)t * OUTD + o0);
    rt[(size_t)(o0 + 0) * IND + t] = f2bf(v.x);
    rt[(size_t)(o0 + 1) * IND + t] = f2bf(v.y);
    rt[(size_t)(o0 + 2) * IND + t] = f2bf(v.z);
    rt[(size_t)(o0 + 3) * IND + t] = f2bf(v.w);
  }
}

// ---------- per-relation gather-GEMM: pk_add_bf16 scatter of (msg/deg) into accb ----------
__global__ __launch_bounds__(256) void k_msgs(
    const float* __restrict__ x, const unsigned short* __restrict__ wt,
    const int* __restrict__ esrc, const int* __restrict__ edst,
    const float* __restrict__ deg, unsigned* __restrict__ accb) {
  __shared__ unsigned short Al[64 * 256];   // 32 KB: x-tile, then reused as msg-tile
  __shared__ int   dstl[64];
  __shared__ float invl[64];
  const int t = threadIdx.x;
  // XCD swizzle: contiguous 2504-block chunk (8 whole relations) per XCD
  const int bid = blockIdx.x;
  const int wg = (bid & 7) * ((RR * EBLK) >> 3) + (bid >> 3);
  const int r  = wg / EBLK;
  const int eb = wg - r * EBLK;

  if (t < 64) {
    const int e = eb * 64 + t;
    int d = -1; float iv = 0.f;
    if (e < EE) { d = edst[(size_t)r * EE + e]; iv = 1.0f / deg[d]; }
    dstl[t] = d; invl[t] = iv;
  }
  {
    const int row = t >> 2, c4 = t & 3;
    const int e = eb * 64 + row;
    const int src = (e < EE) ? esrc[(size_t)r * EE + e] : -1;
    const bool ok = src >= 0;
    const float* xr = x + (size_t)(ok ? src : 0) * IND;
#pragma unroll
    for (int j = 0; j < 8; ++j) {
      const int chunk = c4 * 8 + j;            // 16B = 8 bf16 along k
      union { bf16x8 v; unsigned short u[8]; } pk;
      if (ok) {
        float4 v0 = *reinterpret_cast<const float4*>(xr + chunk * 8);
        float4 v1 = *reinterpret_cast<const float4*>(xr + chunk * 8 + 4);
        pk.u[0]=f2bf(v0.x); pk.u[1]=f2bf(v0.y); pk.u[2]=f2bf(v0.z); pk.u[3]=f2bf(v0.w);
        pk.u[4]=f2bf(v1.x); pk.u[5]=f2bf(v1.y); pk.u[6]=f2bf(v1.z); pk.u[7]=f2bf(v1.w);
      } else {
#pragma unroll
        for (int q = 0; q < 8; ++q) pk.u[q] = 0;
      }
      const int sw = chunk ^ (row & 7);
      *reinterpret_cast<bf16x8*>(&Al[row * 256 + sw * 8]) = pk.v;
    }
  }
  __syncthreads();
  const int lane = t & 63, wave = t >> 6;
  const int n0 = wave * 64;
  const int lc = lane & 15, lg = lane >> 4;
  const unsigned short* Bt = wt + (size_t)r * (OUTD * IND);
  f32x4 acc[4][4];
  const f32x4 zf = {0.f, 0.f, 0.f, 0.f};
#pragma unroll
  for (int m = 0; m < 4; ++m)
#pragma unroll
    for (int n = 0; n < 4; ++n) acc[m][n] = zf;
#pragma unroll
  for (int ks = 0; ks < 8; ++ks) {
    bf16x8 af[4], bfr[4];
#pragma unroll
    for (int m = 0; m < 4; ++m) {
      const int arow = m * 16 + lc;
      const int sw = (ks * 4 + lg) ^ (arow & 7);
      af[m] = *reinterpret_cast<const bf16x8*>(&Al[arow * 256 + sw * 8]);
    }
#pragma unroll
    for (int n = 0; n < 4; ++n) {
      const int o = n0 + n * 16 + lc;
      bfr[n] = *reinterpret_cast<const bf16x8*>(&Bt[(size_t)o * IND + ks * 32 + lg * 8]);
    }
#pragma unroll
    for (int m = 0; m < 4; ++m)
#pragma unroll
      for (int n = 0; n < 4; ++n)
        acc[m][n] = __builtin_amdgcn_mfma_f32_16x16x32_bf16(af[m], bfr[n], acc[m][n], 0, 0, 0);
  }
  // ---- transpose epilogue: scale by 1/deg, round to bf16, stage in LDS (reuse Al) ----
  __syncthreads();   // all MFMA LDS reads done before overwrite
#pragma unroll
  for (int m = 0; m < 4; ++m) {
#pragma unroll
    for (int j = 0; j < 4; ++j) {
      const int row = m * 16 + lg * 4 + j;
      const float iv = invl[row];
#pragma unroll
      for (int n = 0; n < 4; ++n) {
        const int col = n0 + n * 16 + lc;
        const int a16 = row * 256 + ((((col >> 3) ^ (row & 7)) << 3) | (col & 7));
        Al[a16] = f2bf(acc[m][n][j] * iv);
      }
    }
  }
  __syncthreads();
  // ---- pk_add_bf16 scatter: each wave owns 16 edge rows; 2 line-merged atomics/row ----
  const unsigned* Mu = reinterpret_cast<const unsigned*>(Al);
  for (int i = 0; i < 16; ++i) {
    const int e = wave * 16 + i;
    const int d = dstl[e];
    if (d < 0) continue;
    unsigned* orow = accb + (size_t)d * 128;
#pragma unroll
    for (int h = 0; h < 2; ++h) {
      const int c = h * 64 + lane;         // u32 index in the 256-col row
      const int col = 2 * c;
      const int a16 = e * 256 + ((((col >> 3) ^ (e & 7)) << 3) | (col & 7));
      const unsigned v = Mu[a16 >> 1];     // bf16 pair (col, col+1)
      unsigned* p = orow + c;
      asm volatile("global_atomic_pk_add_bf16 %0, %1, off sc1"
                   :: "v"(p), "v"(v) : "memory");
    }
  }
  asm volatile("s_waitcnt vmcnt(0)" ::: "memory");  // drain fire-and-forget atomics
}

// ---------- out = x @ root + accb (agg already /deg) ----------
__global__ __launch_bounds__(256) void k_final(
    const float* __restrict__ x, const unsigned short* __restrict__ rt,
    const unsigned short* __restrict__ ab, float* __restrict__ out) {
  __shared__ unsigned short Al[64 * 256];
  const int t = threadIdx.x;
  const int m0 = blockIdx.x * 64;
  {
    const int row = t >> 2, c4 = t & 3;
    const int grow = m0 + row;
    const bool ok = grow < NN;
    const float* xr = x + (size_t)grow * IND;
#pragma unroll
    for (int j = 0; j < 8; ++j) {
      const int chunk = c4 * 8 + j;
      union { bf16x8 v; unsigned short u[8]; } pk;
      if (ok) {
        float4 v0 = *reinterpret_cast<const float4*>(xr + chunk * 8);
        float4 v1 = *reinterpret_cast<const float4*>(xr + chunk * 8 + 4);
        pk.u[0]=f2bf(v0.x); pk.u[1]=f2bf(v0.y); pk.u[2]=f2bf(v0.z); pk.u[3]=f2bf(v0.w);
        pk.u[4]=f2bf(v1.x); pk.u[5]=f2bf(v1.y); pk.u[6]=f2bf(v1.z); pk.u[7]=f2bf(v1.w);
      } else {
#pragma unroll
        for (int q = 0; q < 8; ++q) pk.u[q] = 0;
      }
      const int sw = chunk ^ (row & 7);
      *reinterpret_cast<bf16x8*>(&Al[row * 256 + sw * 8]) = pk.v;
    }
  }
  __syncthreads();
  const int lane = t & 63, wave = t >> 6;
  const int n0 = wave * 64;
  const int lc = lane & 15, lg = lane >> 4;
  f32x4 acc[4][4];
  const f32x4 zf = {0.f, 0.f, 0.f, 0.f};
#pragma unroll
  for (int m = 0; m < 4; ++m)
#pragma unroll
    for (int n = 0; n < 4; ++n) acc[m][n] = zf;
#pragma unroll
  for (int ks = 0; ks < 8; ++ks) {
    bf16x8 af[4], bfr[4];
#pragma unroll
    for (int m = 0; m < 4; ++m) {
      const int arow = m * 16 + lc;
      const int sw = (ks * 4 + lg) ^ (arow & 7);
      af[m] = *reinterpret_cast<const bf16x8*>(&Al[arow * 256 + sw * 8]);
    }
#pragma unroll
    for (int n = 0; n < 4; ++n) {
      const int o = n0 + n * 16 + lc;
      bfr[n] = *reinterpret_cast<const bf16x8*>(&rt[(size_t)o * IND + ks * 32 + lg * 8]);
    }
#pragma unroll
    for (int m = 0; m < 4; ++m)
#pragma unroll
      for (int n = 0; n < 4; ++n)
        acc[m][n] = __builtin_amdgcn_mfma_f32_16x16x32_bf16(af[m], bfr[n], acc[m][n], 0, 0, 0);
  }
#pragma unroll
  for (int m = 0; m < 4; ++m) {
#pragma unroll
    for (int j = 0; j < 4; ++j) {
      const int row = m0 + m * 16 + lg * 4 + j;
      if (row < NN) {
        const unsigned short* arow = ab + (size_t)row * OUTD + n0 + lc;
        float* orow = out + (size_t)row * OUTD + n0 + lc;
        orow[0]  = acc[m][0][j] + bf2f(arow[0]);
        orow[16] = acc[m][1][j] + bf2f(arow[16]);
        orow[32] = acc[m][2][j] + bf2f(arow[32]);
        orow[48] = acc[m][3][j] + bf2f(arow[48]);
      }
    }
  }
}

extern "C" void kernel_launch(void* const* d_in, const int* in_sizes, int n_in,
                              void* d_out, int out_size, void* d_ws, size_t ws_size,
                              hipStream_t stream) {
  (void)in_sizes; (void)n_in; (void)out_size; (void)ws_size;
  const float* x     = (const float*)d_in[0];
  const float* att   = (const float*)d_in[1];
  const float* basis = (const float*)d_in[2];
  const float* root  = (const float*)d_in[3];
  const float* deg   = (const float*)d_in[4];
  const int*   esrc  = (const int*)d_in[5];
  const int*   edst  = (const int*)d_in[6];
  unsigned short* wt = (unsigned short*)d_ws;                 // [R][OUT][IN] bf16, 8.39 MB
  unsigned short* rt = wt + (size_t)RR * OUTD * IND;          // [OUT][IN]  bf16, 128 KB
  unsigned* accb = (unsigned*)(rt + (size_t)OUTD * IND);      // [N][128] u32 (bf16 pairs), 25.6 MB
  float* out = (float*)d_out;

  hipLaunchKernelGGL(k_build, dim3(256), dim3(256), 0, stream, att, basis, root, wt, rt);
  hipMemsetAsync(accb, 0, (size_t)NN * 128 * 4, stream);
  hipLaunchKernelGGL(k_msgs, dim3(RR * EBLK), dim3(256), 0, stream,
                     x, wt, esrc, edst, deg, accb);
  hipLaunchKernelGGL(k_final, dim3((NN + 63) / 64), dim3(256), 0, stream,
                     x, rt, (const unsigned short*)accb, out);
}